// Round 5
// baseline (119.417 us; speedup 1.0000x reference)
//
#include <hip/hip_runtime.h>
#include <math.h>

#define P      512
#define NA     180
#define NB     4
#define FOFF4  64               // leading zero-pad floats per angle row (16 positions x 4 batches)
#define FS4    (FOFF4 + 4 * P + FOFF4)   // 2176 floats: pad + 4-batch-interleaved data + pad
#define GUARD  512              // float guard before fil2 for window-staging underreach
#define TS     16               // backprojection pixel tile 16x16 (1024 blocks)
#define WPOS   28               // window positions per angle
#define WSF4   (WPOS * 4)       // 112 floats per angle (28 positions x 4 batches)
#define ASEG   60               // angles staged per LDS round (3 segments)
#define NTILES (32 * 32)

#if __has_builtin(__builtin_amdgcn_fractf)
#define FRACT(x) __builtin_amdgcn_fractf(x)
#else
#define FRACT(x) ((x) - floorf(x))
#endif

typedef float f4 __attribute__((ext_vector_type(4), aligned(16)));

static __device__ __forceinline__ f4 fma4(float s, f4 b, f4 c) {
    f4 r;
    r.x = fmaf(s, b.x, c.x); r.y = fmaf(s, b.y, c.y);
    r.z = fmaf(s, b.z, c.z); r.w = fmaf(s, b.w, c.w);
    return r;
}

// ===========================================================================
// Compile-time tables (unchanged from r3): hr (Shepp-Logan ramp impulse
// response) and the angle sin/cos table are input-independent constexpr
// __constant__ data. f64 Taylor sin/cos (quarter-wave reduced) ~1 ulp.
// ===========================================================================
constexpr double PI_D = 3.14159265358979323846264338327950288;

struct D512 { double v[512]; };
struct F512 { float v[512]; };
struct SCT2 { float sc[NA][2]; };

constexpr double cosap(double x) {   // |x| <= ~pi/2, Taylor to x^24
    double invf[13] = {};
    double f = 1.0; invf[0] = 1.0;
    for (int n = 1; n <= 12; ++n) { f *= (double)((2 * n - 1) * (2 * n)); invf[n] = 1.0 / f; }
    const double x2 = x * x;
    double r = invf[12];
    for (int n = 11; n >= 0; --n) r = invf[n] - x2 * r;
    return r;
}
constexpr double sinap(double x) {   // |x| <= ~pi/2, Taylor to x^25
    double invf[13] = {};
    double f = 1.0; invf[0] = 1.0;
    for (int n = 1; n <= 12; ++n) { f *= (double)((2 * n) * (2 * n + 1)); invf[n] = 1.0 / f; }
    const double x2 = x * x;
    double r = invf[12];
    for (int n = 11; n >= 0; --n) r = invf[n] - x2 * r;
    return x * r;
}

constexpr D512 make_ct() {           // cos(2*pi*ph/512), quarter-wave reduced
    D512 t{};
    for (int ph = 0; ph < 512; ++ph) {
        const int q = ph >> 7, r = ph & 127;
        double v = 0.0;
        if (q == 0)      v =  cosap(PI_D * (double)r / 256.0);
        else if (q == 1) v = -cosap(PI_D * (double)(128 - r) / 256.0);
        else if (q == 2) v = -cosap(PI_D * (double)r / 256.0);
        else             v =  cosap(PI_D * (double)(128 - r) / 256.0);
        t.v[ph] = v;
    }
    return t;
}
constexpr D512 CT = make_ct();

constexpr F512 make_ffg() {
    F512 t{};
    double fv[128] = {};
    for (int mm = 0; mm < 128; ++mm) {
        const double pn = PI_D * (double)(2 * mm + 1);
        fv[mm] = -1.0 / (pn * pn);
    }
    for (int o = 0; o <= 256; ++o) {
        double s = 0.0;
        for (int mm = 0; mm < 128; ++mm)
            s += fv[mm] * CT.v[(o * (2 * mm + 1)) & 511];
        double ff = 0.5 + 4.0 * s;           // 0.5 + 2*(2*s_half)
        if (o > 0) {
            const double w = PI_D * (double)o / 512.0;
            ff *= sinap(w) / w;
        }
        t.v[o] = (float)ff;
    }
    for (int o = 257; o < 512; ++o) t.v[o] = t.v[512 - o];
    return t;
}
constexpr F512 FFG = make_ffg();

constexpr F512 make_hr_part(int lo, int hi) {
    F512 t{};
    for (int o = lo; o < hi; ++o) {
        double s2 = 0.0;
        for (int k = 1; k < 256; ++k)
            s2 += (double)FFG.v[k] * CT.v[(o * k) & 511];
        double s = (double)FFG.v[0] + (double)FFG.v[256] * CT.v[(o * 256) & 511] + 2.0 * s2;
        t.v[o] = (float)(s / 512.0);
    }
    return t;
}
constexpr F512 HR_A = make_hr_part(0, 129);
constexpr F512 HR_B = make_hr_part(129, 257);

constexpr F512 make_hr() {
    F512 t{};
    for (int o = 0; o < 129; ++o)   t.v[o] = HR_A.v[o];
    for (int o = 129; o < 257; ++o) t.v[o] = HR_B.v[o];
    for (int o = 257; o < 512; ++o) t.v[o] = t.v[512 - o];
    return t;
}
__constant__ F512 HRC = make_hr();

constexpr SCT2 make_sct() {
    SCT2 t{};
    for (int a = 0; a < NA; ++a) {
        const float thf = (float)a * (float)(PI_D / 179.0);
        const double x = (double)thf;        // in [0, ~pi]
        double sv, cv;
        if (x <= PI_D * 0.5) { sv = sinap(x);        cv =  cosap(x); }
        else                 { sv = sinap(PI_D - x); cv = -cosap(PI_D - x); }
        t.sc[a][0] = (float)sv;
        t.sc[a][1] = (float)cv;
    }
    return t;
}
__constant__ SCT2 SCT = make_sct();

// ---------------------------------------------------------------------------
// K2 (unchanged from r3): one 512-thread block per angle: circular conv for
// ALL 4 batches, hr from __constant__, rolling register window -> ONE
// ds_read_b128 per K-step per thread. Output 4-batch interleaved, staged
// through LDS for coalesced dwordx4 stores. qbt build fused in the tail.
// ---------------------------------------------------------------------------
__global__ __launch_bounds__(512) void ir_filter(const float* __restrict__ sino,
                                                 float* __restrict__ fil2,
                                                 float* __restrict__ qbt) {
    __shared__ __align__(16) float row2[4][2 * P];
    __shared__ __align__(16) float sOut[4 * P];
    const int a = blockIdx.x;
    const int t = threadIdx.x;

    const int b = t >> 7;             // batch 0..3
    const int tt = t & 127;           // outputs 4tt..4tt+3

    const float* src = sino + ((size_t)b * NA + a) * P;
    const float4 v = *(const float4*)(src + 4 * tt);
    *(float4*)&row2[b][4 * tt] = v;
    *(float4*)&row2[b][4 * tt + P] = v;
    __syncthreads();

    const int base0 = P + 4 * tt;
    float4 A = *(const float4*)&row2[b][base0];    // window floats w[0..3]
    float a0 = 0.f, a1 = 0.f, a2 = 0.f, a3 = 0.f;
    #pragma unroll 4
    for (int J = 0; J < P; J += 4) {
        const float4 Bv = *(const float4*)&row2[b][base0 - J - 4];  // w[-4..-1]
        const float h0 = HRC.v[J], h1 = HRC.v[J + 1], h2v = HRC.v[J + 2], h3 = HRC.v[J + 3];
        a0 = fmaf(h0, A.x, a0); a0 = fmaf(h1, Bv.w, a0); a0 = fmaf(h2v, Bv.z, a0); a0 = fmaf(h3, Bv.y, a0);
        a1 = fmaf(h0, A.y, a1); a1 = fmaf(h1, A.x, a1); a1 = fmaf(h2v, Bv.w, a1); a1 = fmaf(h3, Bv.z, a1);
        a2 = fmaf(h0, A.z, a2); a2 = fmaf(h1, A.y, a2); a2 = fmaf(h2v, A.x, a2); a2 = fmaf(h3, Bv.w, a2);
        a3 = fmaf(h0, A.w, a3); a3 = fmaf(h1, A.z, a3); a3 = fmaf(h2v, A.y, a3); a3 = fmaf(h3, A.x, a3);
        A = Bv;                                    // slide the register window
    }
    const int o0 = 16 * tt + b;
    sOut[o0]      = a0;
    sOut[o0 + 4]  = a1;
    sOut[o0 + 8]  = a2;
    sOut[o0 + 12] = a3;
    __syncthreads();

    float* frow = fil2 + (size_t)a * FS4;
    *(f4*)(frow + FOFF4 + 4 * t) = *(const f4*)(sOut + 4 * t);   // coalesced
    if (t < FOFF4) {                  // zero pads (ws re-poisoned every call)
        frow[t] = 0.f;
        frow[FOFF4 + 4 * P + t] = 0.f;
    }

    // fused window-base table for this angle
    const float sa = SCT.sc[a][0];
    const float ca = SCT.sc[a][1];
    #pragma unroll
    for (int i = 0; i < 2; ++i) {
        const int tile = t + 512 * i;          // by*32+bx
        const int bx = tile & 31, by = tile >> 5;
        const float xlo = (float)(240 - 16 * bx);   // min x over tile
        const float ylo = (float)(16 * by - 256);
        const float yhi = (float)(16 * by - 241);
        const float pmin = fmaf(sa, xlo, fminf(ca * ylo, ca * yhi) + 256.0f);
        const int base = ((int)floorf(pmin) - 2) & ~1;  // even, fp-slop safety
        qbt[tile * NA + a] = (float)(256 - base);
    }
}

// ---------------------------------------------------------------------------
// Backprojection tap helpers. ang_plain == r3's per-pixel path (2 b128).
// ang_shared serves a VERTICAL pixel pair (rows h, h+1) with 3 b128: their
// q differ by ~cos(th), |c|<=0.999 on the angles where it's used, so the
// pair's 4 tap positions fit in {jm, jm+1, jm+2}. Tap values and fmaf order
// are identical to ang_plain -> bit-exact output.
// ---------------------------------------------------------------------------
__device__ __forceinline__ void ang_plain(const float* wr, float xf, float yf,
                                          float ss, float cc, float qb, f4& acc) {
    const float q = fmaf(xf, ss, fmaf(yf, cc, qb));
    const int j = (int)q;
    const float fr = FRACT(q);
    const f4 W0 = *(const f4*)(wr + 4 * j);
    const f4 W1 = *(const f4*)(wr + 4 * j + 4);
    acc = fma4(1.f - fr, W0, fma4(fr, W1, acc));
}

template <bool CPOS>   // CPOS: cc >= 0 (static per angle range)
__device__ __forceinline__ void ang_shared(const float* wr, float xf, float yf0, float yf1,
                                           float ss, float cc, float qb,
                                           f4& accT, f4& accB) {
    const float q0 = fmaf(xf, ss, fmaf(yf0, cc, qb));   // row h   (top)
    const float q1 = fmaf(xf, ss, fmaf(yf1, cc, qb));   // row h+1 (bottom)
    const int j0 = (int)q0, j1 = (int)q1;
    const float fr0 = FRACT(q0), fr1 = FRACT(q1);
    const float of0 = 1.f - fr0, of1 = 1.f - fr1;
    const int jm = CPOS ? j0 : j1;                      // min of the two
    const f4 R0 = *(const f4*)(wr + 4 * jm);
    const f4 R1 = *(const f4*)(wr + 4 * jm + 4);
    const f4 R2 = *(const f4*)(wr + 4 * jm + 8);
    if (CPOS) {                                         // q1 >= q0
        const bool d = (j1 != j0);
        const f4 X0 = d ? R1 : R0;
        const f4 X1 = d ? R2 : R1;
        accT = fma4(of0, R0, fma4(fr0, R1, accT));
        accB = fma4(of1, X0, fma4(fr1, X1, accB));
    } else {                                            // q0 >= q1
        const bool d = (j0 != j1);
        const f4 X0 = d ? R1 : R0;
        const f4 X1 = d ? R2 : R1;
        accT = fma4(of0, X0, fma4(fr0, X1, accT));
        accB = fma4(of1, R0, fma4(fr1, R1, accB));
    }
}

// ---------------------------------------------------------------------------
// K3: backprojection, 4 batches + VERTICAL PIXEL PAIR per thread: 128
// threads cover a 16x16 tile (16 cols x 8 row-pairs), 1024 blocks (4/CU,
// 8 waves/CU, LDS 26.9KB). Pair-sharing cuts the dominating LDS tap pipe
// from 4 to 3 ds_read_b128 per pair on 174/180 angles; angles {0,1,2,
// 177,178,179} (|cos|>0.999) use the plain path (j-span safety), and the
// cos-sign split at a=90 is compile-time static.
// ---------------------------------------------------------------------------
__global__ __launch_bounds__(128) void ir_backproject(const float* __restrict__ fil2,
                                                      const float* __restrict__ qbt,
                                                      float* __restrict__ out) {
    __shared__ __align__(16) float win[ASEG * WSF4 + 16];   // 26.9 KB + slack

    const int t = threadIdx.x;
    const int w0 = blockIdx.x * TS, h0 = blockIdx.y * TS;
    const float* qrow = qbt + (blockIdx.y * 32 + blockIdx.x) * NA;  // this tile's bases

    const int w = w0 + (t & 15);
    const int r = t >> 4;                // row pair 0..7
    const int h = h0 + 2 * r;

    const int ix = 255 - w;              // reversed x axis
    const int iy0 = h - 256;
    const int iy1 = iy0 + 1;
    const int m0 = (ix * ix + iy0 * iy0) <= 256 * 256;
    const int m1 = (ix * ix + iy1 * iy1) <= 256 * 256;

    float* o0 = out + (size_t)h * P + w;

    if (__syncthreads_count(m0 | m1) == 0) {   // tile fully outside circle
        #pragma unroll
        for (int b = 0; b < 4; ++b) {
            o0[(size_t)b * P * P]     = 0.f;
            o0[(size_t)b * P * P + P] = 0.f;
        }
        return;
    }

    const float xf = (float)ix;
    const float yf0 = (float)iy0;
    const float yf1 = (float)iy1;
    f4 accT = {0.f, 0.f, 0.f, 0.f};
    f4 accB = {0.f, 0.f, 0.f, 0.f};

    #pragma unroll
    for (int seg = 0; seg < 3; ++seg) {
        const int A0 = seg * ASEG;

        // Phase B: stage this segment's 4-batch windows (16B-aligned chunks)
        for (int idx = t; idx < ASEG * WPOS; idx += 128) {
            const int al = idx / WPOS;
            const int i = idx - al * WPOS;
            const int a = A0 + al;
            const int base = 256 - (int)qrow[a];          // lane-varying -> v-load
            const int off = a * FS4 + FOFF4 + 4 * (base + i);  // 16B aligned
            const f4 vv = *(const f4*)(fil2 + off);
            *(f4*)(win + al * WSF4 + 4 * i) = vv;
        }
        __syncthreads();

        // Phase C: static angle schedule.
        //  seg0: a 0..2 plain, 3..59 shared<c>=0>
        //  seg1: a 60..89 shared<c>=0>, 90..119 shared<c<0>
        //  seg2: a 120..176 shared<c<0>, 177..179 plain
        if (seg == 0) {
            #pragma unroll
            for (int al = 0; al < 3; ++al) {
                const float ss = SCT.sc[al][0], cc = SCT.sc[al][1];
                const float qb = qrow[al];
                const float* wr = win + al * WSF4;
                ang_plain(wr, xf, yf0, ss, cc, qb, accT);
                ang_plain(wr, xf, yf1, ss, cc, qb, accB);
            }
            #pragma unroll 2
            for (int al = 3; al < 60; ++al) {
                const float ss = SCT.sc[al][0], cc = SCT.sc[al][1];
                const float qb = qrow[al];
                ang_shared<true>(win + al * WSF4, xf, yf0, yf1, ss, cc, qb, accT, accB);
            }
        } else if (seg == 1) {
            #pragma unroll 2
            for (int al = 0; al < 30; ++al) {
                const int a = 60 + al;
                const float ss = SCT.sc[a][0], cc = SCT.sc[a][1];
                const float qb = qrow[a];
                ang_shared<true>(win + al * WSF4, xf, yf0, yf1, ss, cc, qb, accT, accB);
            }
            #pragma unroll 2
            for (int al = 30; al < 60; ++al) {
                const int a = 60 + al;
                const float ss = SCT.sc[a][0], cc = SCT.sc[a][1];
                const float qb = qrow[a];
                ang_shared<false>(win + al * WSF4, xf, yf0, yf1, ss, cc, qb, accT, accB);
            }
        } else {
            #pragma unroll 2
            for (int al = 0; al < 57; ++al) {
                const int a = 120 + al;
                const float ss = SCT.sc[a][0], cc = SCT.sc[a][1];
                const float qb = qrow[a];
                ang_shared<false>(win + al * WSF4, xf, yf0, yf1, ss, cc, qb, accT, accB);
            }
            #pragma unroll
            for (int al = 57; al < 60; ++al) {
                const int a = 120 + al;
                const float ss = SCT.sc[a][0], cc = SCT.sc[a][1];
                const float qb = qrow[a];
                const float* wr = win + al * WSF4;
                ang_plain(wr, xf, yf0, ss, cc, qb, accT);
                ang_plain(wr, xf, yf1, ss, cc, qb, accB);
            }
        }
        if (seg < 2) __syncthreads();    // protect win before restage (uniform)
    }

    const float scale = (float)(M_PI / (2.0 * NA));
    o0[0]                     = m0 ? accT.x * scale : 0.f;
    o0[P]                     = m1 ? accB.x * scale : 0.f;
    o0[(size_t)P * P]         = m0 ? accT.y * scale : 0.f;
    o0[(size_t)P * P + P]     = m1 ? accB.y * scale : 0.f;
    o0[(size_t)2 * P * P]     = m0 ? accT.z * scale : 0.f;
    o0[(size_t)2 * P * P + P] = m1 ? accB.z * scale : 0.f;
    o0[(size_t)3 * P * P]     = m0 ? accT.w * scale : 0.f;
    o0[(size_t)3 * P * P + P] = m1 ? accB.w * scale : 0.f;
}

// ---------------------------------------------------------------------------
extern "C" void kernel_launch(void* const* d_in, const int* in_sizes, int n_in,
                              void* d_out, int out_size, void* d_ws, size_t ws_size,
                              hipStream_t stream) {
    const float* sino = (const float*)d_in[0];
    float* out = (float*)d_out;
    float* ws = (float*)d_ws;

    float* qbt   = ws;                        // 1024 tiles * 180 floats
    float* fil2  = ws + NTILES * NA + GUARD;  // 180*2176 floats, 16B aligned

    ir_filter<<<NA, 512, 0, stream>>>(sino, fil2, qbt);

    dim3 gridB(P / TS, P / TS, 1);            // 1024 blocks, pair-of-rows threads
    ir_backproject<<<gridB, 128, 0, stream>>>(fil2, qbt, out);
}

// Round 6
// 104.208 us; speedup vs baseline: 1.1459x; 1.1459x over previous
//
#include <hip/hip_runtime.h>
#include <math.h>

#define P      512
#define NA     180
#define NB     4
#define FOFF4  64               // leading zero-pad floats per angle row (16 positions x 4 batches)
#define FS4    (FOFF4 + 4 * P + FOFF4)   // 2176 floats: pad + 4-batch-interleaved data + pad
#define GUARD  512              // float guard before fil2 for window-staging underreach
#define TS     16               // backprojection pixel tile 16x16 (1024 blocks)
#define WPOS   28               // window positions per angle
#define WSF4   (WPOS * 4)       // 112 floats per angle slot (28 positions x 4 batches)
#define HSEG   30               // angles per half-block per LDS round (3 rounds x 2 halves)
#define NSLOT  (2 * HSEG)       // 60 window slots resident per round
#define NTILES (32 * 32)

#if __has_builtin(__builtin_amdgcn_fractf)
#define FRACT(x) __builtin_amdgcn_fractf(x)
#else
#define FRACT(x) ((x) - floorf(x))
#endif

typedef float f4 __attribute__((ext_vector_type(4), aligned(16)));

// ===========================================================================
// Compile-time tables (unchanged from r3): hr (Shepp-Logan ramp impulse
// response) and the angle sin/cos table are input-independent constexpr
// __constant__ data. f64 Taylor sin/cos (quarter-wave reduced) ~1 ulp.
// ===========================================================================
constexpr double PI_D = 3.14159265358979323846264338327950288;

struct D512 { double v[512]; };
struct F512 { float v[512]; };
struct SCT2 { float sc[NA][2]; };

constexpr double cosap(double x) {   // |x| <= ~pi/2, Taylor to x^24
    double invf[13] = {};
    double f = 1.0; invf[0] = 1.0;
    for (int n = 1; n <= 12; ++n) { f *= (double)((2 * n - 1) * (2 * n)); invf[n] = 1.0 / f; }
    const double x2 = x * x;
    double r = invf[12];
    for (int n = 11; n >= 0; --n) r = invf[n] - x2 * r;
    return r;
}
constexpr double sinap(double x) {   // |x| <= ~pi/2, Taylor to x^25
    double invf[13] = {};
    double f = 1.0; invf[0] = 1.0;
    for (int n = 1; n <= 12; ++n) { f *= (double)((2 * n) * (2 * n + 1)); invf[n] = 1.0 / f; }
    const double x2 = x * x;
    double r = invf[12];
    for (int n = 11; n >= 0; --n) r = invf[n] - x2 * r;
    return x * r;
}

constexpr D512 make_ct() {           // cos(2*pi*ph/512), quarter-wave reduced
    D512 t{};
    for (int ph = 0; ph < 512; ++ph) {
        const int q = ph >> 7, r = ph & 127;
        double v = 0.0;
        if (q == 0)      v =  cosap(PI_D * (double)r / 256.0);
        else if (q == 1) v = -cosap(PI_D * (double)(128 - r) / 256.0);
        else if (q == 2) v = -cosap(PI_D * (double)r / 256.0);
        else             v =  cosap(PI_D * (double)(128 - r) / 256.0);
        t.v[ph] = v;
    }
    return t;
}
constexpr D512 CT = make_ct();

constexpr F512 make_ffg() {
    F512 t{};
    double fv[128] = {};
    for (int mm = 0; mm < 128; ++mm) {
        const double pn = PI_D * (double)(2 * mm + 1);
        fv[mm] = -1.0 / (pn * pn);
    }
    for (int o = 0; o <= 256; ++o) {
        double s = 0.0;
        for (int mm = 0; mm < 128; ++mm)
            s += fv[mm] * CT.v[(o * (2 * mm + 1)) & 511];
        double ff = 0.5 + 4.0 * s;           // 0.5 + 2*(2*s_half)
        if (o > 0) {
            const double w = PI_D * (double)o / 512.0;
            ff *= sinap(w) / w;
        }
        t.v[o] = (float)ff;
    }
    for (int o = 257; o < 512; ++o) t.v[o] = t.v[512 - o];
    return t;
}
constexpr F512 FFG = make_ffg();

constexpr F512 make_hr_part(int lo, int hi) {
    F512 t{};
    for (int o = lo; o < hi; ++o) {
        double s2 = 0.0;
        for (int k = 1; k < 256; ++k)
            s2 += (double)FFG.v[k] * CT.v[(o * k) & 511];
        double s = (double)FFG.v[0] + (double)FFG.v[256] * CT.v[(o * 256) & 511] + 2.0 * s2;
        t.v[o] = (float)(s / 512.0);
    }
    return t;
}
constexpr F512 HR_A = make_hr_part(0, 129);
constexpr F512 HR_B = make_hr_part(129, 257);

constexpr F512 make_hr() {
    F512 t{};
    for (int o = 0; o < 129; ++o)   t.v[o] = HR_A.v[o];
    for (int o = 129; o < 257; ++o) t.v[o] = HR_B.v[o];
    for (int o = 257; o < 512; ++o) t.v[o] = t.v[512 - o];
    return t;
}
__constant__ F512 HRC = make_hr();

constexpr SCT2 make_sct() {
    SCT2 t{};
    for (int a = 0; a < NA; ++a) {
        const float thf = (float)a * (float)(PI_D / 179.0);
        const double x = (double)thf;        // in [0, ~pi]
        double sv, cv;
        if (x <= PI_D * 0.5) { sv = sinap(x);        cv =  cosap(x); }
        else                 { sv = sinap(PI_D - x); cv = -cosap(PI_D - x); }
        t.sc[a][0] = (float)sv;
        t.sc[a][1] = (float)cv;
    }
    return t;
}
__constant__ SCT2 SCT = make_sct();

// ---------------------------------------------------------------------------
// K2 (unchanged from r3): one 512-thread block per angle: circular conv for
// ALL 4 batches, hr from __constant__, rolling register window -> ONE
// ds_read_b128 per K-step per thread. Output 4-batch interleaved, staged
// through LDS for coalesced dwordx4 stores. qbt build fused in the tail.
// ---------------------------------------------------------------------------
__global__ __launch_bounds__(512) void ir_filter(const float* __restrict__ sino,
                                                 float* __restrict__ fil2,
                                                 float* __restrict__ qbt) {
    __shared__ __align__(16) float row2[4][2 * P];
    __shared__ __align__(16) float sOut[4 * P];
    const int a = blockIdx.x;
    const int t = threadIdx.x;

    const int b = t >> 7;             // batch 0..3
    const int tt = t & 127;           // outputs 4tt..4tt+3

    const float* src = sino + ((size_t)b * NA + a) * P;
    const float4 v = *(const float4*)(src + 4 * tt);
    *(float4*)&row2[b][4 * tt] = v;
    *(float4*)&row2[b][4 * tt + P] = v;
    __syncthreads();

    const int base0 = P + 4 * tt;
    float4 A = *(const float4*)&row2[b][base0];    // window floats w[0..3]
    float a0 = 0.f, a1 = 0.f, a2 = 0.f, a3 = 0.f;
    #pragma unroll 4
    for (int J = 0; J < P; J += 4) {
        const float4 Bv = *(const float4*)&row2[b][base0 - J - 4];  // w[-4..-1]
        const float h0 = HRC.v[J], h1 = HRC.v[J + 1], h2v = HRC.v[J + 2], h3 = HRC.v[J + 3];
        a0 = fmaf(h0, A.x, a0); a0 = fmaf(h1, Bv.w, a0); a0 = fmaf(h2v, Bv.z, a0); a0 = fmaf(h3, Bv.y, a0);
        a1 = fmaf(h0, A.y, a1); a1 = fmaf(h1, A.x, a1); a1 = fmaf(h2v, Bv.w, a1); a1 = fmaf(h3, Bv.z, a1);
        a2 = fmaf(h0, A.z, a2); a2 = fmaf(h1, A.y, a2); a2 = fmaf(h2v, A.x, a2); a2 = fmaf(h3, Bv.w, a2);
        a3 = fmaf(h0, A.w, a3); a3 = fmaf(h1, A.z, a3); a3 = fmaf(h2v, A.y, a3); a3 = fmaf(h3, A.x, a3);
        A = Bv;                                    // slide the register window
    }
    const int o0 = 16 * tt + b;
    sOut[o0]      = a0;
    sOut[o0 + 4]  = a1;
    sOut[o0 + 8]  = a2;
    sOut[o0 + 12] = a3;
    __syncthreads();

    float* frow = fil2 + (size_t)a * FS4;
    *(f4*)(frow + FOFF4 + 4 * t) = *(const f4*)(sOut + 4 * t);   // coalesced
    if (t < FOFF4) {                  // zero pads (ws re-poisoned every call)
        frow[t] = 0.f;
        frow[FOFF4 + 4 * P + t] = 0.f;
    }

    // fused window-base table for this angle
    const float sa = SCT.sc[a][0];
    const float ca = SCT.sc[a][1];
    #pragma unroll
    for (int i = 0; i < 2; ++i) {
        const int tile = t + 512 * i;          // by*32+bx
        const int bx = tile & 31, by = tile >> 5;
        const float xlo = (float)(240 - 16 * bx);   // min x over tile
        const float ylo = (float)(16 * by - 256);
        const float yhi = (float)(16 * by - 241);
        const float pmin = fmaf(sa, xlo, fminf(ca * ylo, ca * yhi) + 256.0f);
        const int base = ((int)floorf(pmin) - 2) & ~1;  // even, fp-slop safety
        qbt[tile * NA + a] = (float)(256 - base);
    }
}

// ---------------------------------------------------------------------------
// K3: backprojection, 16x16 tile, 512 threads: INTRA-BLOCK ANGLE SPLIT.
// Threads 0..255 accumulate angles 0..89 for their pixel; threads 256..511
// accumulate angles 90..179 for the SAME pixel set; a 4KB LDS exchange +
// one add combines the halves. Per-angle math, window slots, tap reads and
// fmaf chains are r3's exactly -- only the half-sum add is new (~1e-7).
// 1024 blocks x 8 waves = 32 waves/CU (vs r3's 16): the r5 counters showed
// the tap loop is LATENCY-bound (VALUBusy 26%, LDS conflicts 0, occupancy
// 16%), so doubling resident waves pushes the DS pipe toward its 12cyc/b128
// saturation floor. LDS 26.9KB (2x30 slots) -> 4 blocks/CU = 107.6KB.
// __launch_bounds__(512,8) pins VGPR<=64 so all 8 waves/SIMD fit.
// ---------------------------------------------------------------------------
__global__ __launch_bounds__(512, 8) void ir_backproject(const float* __restrict__ fil2,
                                                         const float* __restrict__ qbt,
                                                         float* __restrict__ out) {
    __shared__ __align__(16) float win[NSLOT * WSF4];   // 26.9 KB, 60 slots

    const int t = threadIdx.x;
    const int half = t >> 8;             // 0: angles 0..89, 1: angles 90..179
    const int tl = t & 255;              // pixel index within tile
    const int w0 = blockIdx.x * TS, h0 = blockIdx.y * TS;
    const float* qrow = qbt + (blockIdx.y * 32 + blockIdx.x) * NA;  // tile bases

    const int w = w0 + (tl & 15);
    const int h = h0 + (tl >> 4);

    const int ix = 255 - w;              // reversed x axis
    const int iy = h - 256;
    const int m = (ix * ix + iy * iy) <= 256 * 256;

    float* o0 = out + (size_t)h * P + w;

    if (__syncthreads_count(m) == 0) {   // tile fully outside circle
        if (t < 256) {
            o0[0] = 0.f;
            o0[(size_t)P * P] = 0.f;
            o0[(size_t)2 * P * P] = 0.f;
            o0[(size_t)3 * P * P] = 0.f;
        }
        return;
    }

    const float xf = (float)ix;
    const float yf = (float)iy;
    f4 acc = {0.f, 0.f, 0.f, 0.f};

    #pragma unroll
    for (int seg = 0; seg < 3; ++seg) {
        const int A0 = seg * HSEG;       // half-local segment start

        // Phase B: stage 60 slots (slots 0..29 -> angles A0.., 30..59 ->
        // angles 90+A0..) with all 512 threads, 16B-aligned chunks.
        for (int idx = t; idx < NSLOT * WPOS; idx += 512) {
            const int sl = idx / WPOS;
            const int i = idx - sl * WPOS;
            const int a = (sl < HSEG) ? (A0 + sl) : (60 + A0 + sl);  // 90+A0+(sl-30)
            const int base = 256 - (int)qrow[a];          // lane-varying -> v-load
            const int off = a * FS4 + FOFF4 + 4 * (base + i);  // 16B aligned
            const f4 vv = *(const f4*)(fil2 + off);
            *(f4*)(win + sl * WSF4 + 4 * i) = vv;
        }
        __syncthreads();

        // Phase C: this half's 30 angles, r3's exact per-angle body.
        const int abase = half * 90 + A0;
        const int sbase = half * HSEG;
        #pragma unroll 5
        for (int al = 0; al < HSEG; ++al) {
            const int a = abase + al;
            const float ss = SCT.sc[a][0];                // wave-uniform -> s_load
            const float cc = SCT.sc[a][1];
            const float qb = qrow[a];                     // wave-uniform -> s_load
            const float q = fmaf(xf, ss, fmaf(yf, cc, qb));
            const int j = (int)q;
            const float fr = FRACT(q);
            const float omf = 1.f - fr;
            const float* wr = win + (sbase + al) * WSF4;
            const f4 W0 = *(const f4*)(wr + 4 * j);
            const f4 W1 = *(const f4*)(wr + 4 * j + 4);
            acc.x = fmaf(omf, W0.x, fmaf(fr, W1.x, acc.x));
            acc.y = fmaf(omf, W0.y, fmaf(fr, W1.y, acc.y));
            acc.z = fmaf(omf, W0.z, fmaf(fr, W1.z, acc.z));
            acc.w = fmaf(omf, W0.w, fmaf(fr, W1.w, acc.w));
        }
        __syncthreads();                 // win reads done before restage/reuse
    }

    // Combine halves: B writes its acc to LDS (4KB), A adds and stores.
    if (t >= 256) *(f4*)(win + 4 * tl) = acc;
    __syncthreads();
    if (t < 256) {
        const f4 b = *(const f4*)(win + 4 * tl);
        const float scale = (float)(M_PI / (2.0 * NA));
        o0[0]                 = m ? (acc.x + b.x) * scale : 0.f;
        o0[(size_t)P * P]     = m ? (acc.y + b.y) * scale : 0.f;
        o0[(size_t)2 * P * P] = m ? (acc.z + b.z) * scale : 0.f;
        o0[(size_t)3 * P * P] = m ? (acc.w + b.w) * scale : 0.f;
    }
}

// ---------------------------------------------------------------------------
extern "C" void kernel_launch(void* const* d_in, const int* in_sizes, int n_in,
                              void* d_out, int out_size, void* d_ws, size_t ws_size,
                              hipStream_t stream) {
    const float* sino = (const float*)d_in[0];
    float* out = (float*)d_out;
    float* ws = (float*)d_ws;

    float* qbt   = ws;                        // 1024 tiles * 180 floats
    float* fil2  = ws + NTILES * NA + GUARD;  // 180*2176 floats, 16B aligned

    ir_filter<<<NA, 512, 0, stream>>>(sino, fil2, qbt);

    dim3 gridB(P / TS, P / TS, 1);            // 1024 blocks, angle-split in-block
    ir_backproject<<<gridB, 512, 0, stream>>>(fil2, qbt, out);
}

// Round 7
// 104.034 us; speedup vs baseline: 1.1479x; 1.0017x over previous
//
#include <hip/hip_runtime.h>
#include <math.h>

#define P      512
#define NA     180
#define NB     4
#define FOFFH  64               // leading zero-pad HALVES per angle row (16 positions x 4 batches)
#define FSH    (FOFFH + 4 * P + FOFFH)   // 2176 halves: pad + 4-batch-interleaved fp16 data + pad
#define GUARD  512              // float guard before fil2h for window-staging underreach
#define TS     16               // backprojection pixel tile 16x16 (1024 blocks)
#define WPOS   28               // window positions per angle
#define WCHK   (WPOS / 2)       // 14 x 16B staging chunks per angle (2 positions each)
#define WSH    (WPOS * 4)       // 112 halves per angle slot (28 positions x 4 batches)
#define ASEG   60               // angles staged per LDS round (3 segments)
#define NTILES (32 * 32)

#if __has_builtin(__builtin_amdgcn_fractf)
#define FRACT(x) __builtin_amdgcn_fractf(x)
#else
#define FRACT(x) ((x) - floorf(x))
#endif

typedef float f4 __attribute__((ext_vector_type(4), aligned(16)));
typedef _Float16 h4 __attribute__((ext_vector_type(4), aligned(8)));

// ===========================================================================
// Compile-time tables (unchanged from r3): hr (Shepp-Logan ramp impulse
// response) and the angle sin/cos table are input-independent constexpr
// __constant__ data. f64 Taylor sin/cos (quarter-wave reduced) ~1 ulp.
// ===========================================================================
constexpr double PI_D = 3.14159265358979323846264338327950288;

struct D512 { double v[512]; };
struct F512 { float v[512]; };
struct SCT2 { float sc[NA][2]; };

constexpr double cosap(double x) {   // |x| <= ~pi/2, Taylor to x^24
    double invf[13] = {};
    double f = 1.0; invf[0] = 1.0;
    for (int n = 1; n <= 12; ++n) { f *= (double)((2 * n - 1) * (2 * n)); invf[n] = 1.0 / f; }
    const double x2 = x * x;
    double r = invf[12];
    for (int n = 11; n >= 0; --n) r = invf[n] - x2 * r;
    return r;
}
constexpr double sinap(double x) {   // |x| <= ~pi/2, Taylor to x^25
    double invf[13] = {};
    double f = 1.0; invf[0] = 1.0;
    for (int n = 1; n <= 12; ++n) { f *= (double)((2 * n) * (2 * n + 1)); invf[n] = 1.0 / f; }
    const double x2 = x * x;
    double r = invf[12];
    for (int n = 11; n >= 0; --n) r = invf[n] - x2 * r;
    return x * r;
}

constexpr D512 make_ct() {           // cos(2*pi*ph/512), quarter-wave reduced
    D512 t{};
    for (int ph = 0; ph < 512; ++ph) {
        const int q = ph >> 7, r = ph & 127;
        double v = 0.0;
        if (q == 0)      v =  cosap(PI_D * (double)r / 256.0);
        else if (q == 1) v = -cosap(PI_D * (double)(128 - r) / 256.0);
        else if (q == 2) v = -cosap(PI_D * (double)r / 256.0);
        else             v =  cosap(PI_D * (double)(128 - r) / 256.0);
        t.v[ph] = v;
    }
    return t;
}
constexpr D512 CT = make_ct();

constexpr F512 make_ffg() {
    F512 t{};
    double fv[128] = {};
    for (int mm = 0; mm < 128; ++mm) {
        const double pn = PI_D * (double)(2 * mm + 1);
        fv[mm] = -1.0 / (pn * pn);
    }
    for (int o = 0; o <= 256; ++o) {
        double s = 0.0;
        for (int mm = 0; mm < 128; ++mm)
            s += fv[mm] * CT.v[(o * (2 * mm + 1)) & 511];
        double ff = 0.5 + 4.0 * s;           // 0.5 + 2*(2*s_half)
        if (o > 0) {
            const double w = PI_D * (double)o / 512.0;
            ff *= sinap(w) / w;
        }
        t.v[o] = (float)ff;
    }
    for (int o = 257; o < 512; ++o) t.v[o] = t.v[512 - o];
    return t;
}
constexpr F512 FFG = make_ffg();

constexpr F512 make_hr_part(int lo, int hi) {
    F512 t{};
    for (int o = lo; o < hi; ++o) {
        double s2 = 0.0;
        for (int k = 1; k < 256; ++k)
            s2 += (double)FFG.v[k] * CT.v[(o * k) & 511];
        double s = (double)FFG.v[0] + (double)FFG.v[256] * CT.v[(o * 256) & 511] + 2.0 * s2;
        t.v[o] = (float)(s / 512.0);
    }
    return t;
}
constexpr F512 HR_A = make_hr_part(0, 129);
constexpr F512 HR_B = make_hr_part(129, 257);

constexpr F512 make_hr() {
    F512 t{};
    for (int o = 0; o < 129; ++o)   t.v[o] = HR_A.v[o];
    for (int o = 129; o < 257; ++o) t.v[o] = HR_B.v[o];
    for (int o = 257; o < 512; ++o) t.v[o] = t.v[512 - o];
    return t;
}
__constant__ F512 HRC = make_hr();

constexpr SCT2 make_sct() {
    SCT2 t{};
    for (int a = 0; a < NA; ++a) {
        const float thf = (float)a * (float)(PI_D / 179.0);
        const double x = (double)thf;        // in [0, ~pi]
        double sv, cv;
        if (x <= PI_D * 0.5) { sv = sinap(x);        cv =  cosap(x); }
        else                 { sv = sinap(PI_D - x); cv = -cosap(PI_D - x); }
        t.sc[a][0] = (float)sv;
        t.sc[a][1] = (float)cv;
    }
    return t;
}
__constant__ SCT2 SCT = make_sct();

// ---------------------------------------------------------------------------
// K2: one 512-thread block per angle: circular conv for ALL 4 batches, f32
// rolling-register-window chain bit-identical to r3. Output is now FP16,
// 4-batch interleaved (half index FOFFH + 4*pos + b): the conv result is
// rounded once (_Float16 rn) at store. 8B/lane coalesced stores. qbt build
// fused in the tail (unchanged).
// ---------------------------------------------------------------------------
__global__ __launch_bounds__(512) void ir_filter(const float* __restrict__ sino,
                                                 _Float16* __restrict__ fil2h,
                                                 float* __restrict__ qbt) {
    __shared__ __align__(16) float row2[4][2 * P];
    __shared__ __align__(16) float sOut[4 * P];
    const int a = blockIdx.x;
    const int t = threadIdx.x;

    const int b = t >> 7;             // batch 0..3
    const int tt = t & 127;           // outputs 4tt..4tt+3

    const float* src = sino + ((size_t)b * NA + a) * P;
    const float4 v = *(const float4*)(src + 4 * tt);
    *(float4*)&row2[b][4 * tt] = v;
    *(float4*)&row2[b][4 * tt + P] = v;
    __syncthreads();

    const int base0 = P + 4 * tt;
    float4 A = *(const float4*)&row2[b][base0];    // window floats w[0..3]
    float a0 = 0.f, a1 = 0.f, a2 = 0.f, a3 = 0.f;
    #pragma unroll 4
    for (int J = 0; J < P; J += 4) {
        const float4 Bv = *(const float4*)&row2[b][base0 - J - 4];  // w[-4..-1]
        const float h0 = HRC.v[J], h1 = HRC.v[J + 1], h2v = HRC.v[J + 2], h3 = HRC.v[J + 3];
        a0 = fmaf(h0, A.x, a0); a0 = fmaf(h1, Bv.w, a0); a0 = fmaf(h2v, Bv.z, a0); a0 = fmaf(h3, Bv.y, a0);
        a1 = fmaf(h0, A.y, a1); a1 = fmaf(h1, A.x, a1); a1 = fmaf(h2v, Bv.w, a1); a1 = fmaf(h3, Bv.z, a1);
        a2 = fmaf(h0, A.z, a2); a2 = fmaf(h1, A.y, a2); a2 = fmaf(h2v, A.x, a2); a2 = fmaf(h3, Bv.w, a2);
        a3 = fmaf(h0, A.w, a3); a3 = fmaf(h1, A.z, a3); a3 = fmaf(h2v, A.y, a3); a3 = fmaf(h3, A.x, a3);
        A = Bv;                                    // slide the register window
    }
    // interleave via LDS: float index in data region = 4*pos + b, pos = 4tt+d
    const int o0 = 16 * tt + b;
    sOut[o0]      = a0;
    sOut[o0 + 4]  = a1;
    sOut[o0 + 8]  = a2;
    sOut[o0 + 12] = a3;
    __syncthreads();

    _Float16* frowh = fil2h + (size_t)a * FSH;
    const float4 sv = *(const float4*)(sOut + 4 * t);
    h4 hv;
    hv.x = (_Float16)sv.x; hv.y = (_Float16)sv.y;
    hv.z = (_Float16)sv.z; hv.w = (_Float16)sv.w;
    *(h4*)(frowh + FOFFH + 4 * t) = hv;            // 8B coalesced
    if (t < FOFFH) {                  // zero pads (ws re-poisoned every call)
        frowh[t] = (_Float16)0.f;
        frowh[FOFFH + 4 * P + t] = (_Float16)0.f;
    }

    // fused window-base table for this angle (unchanged)
    const float sa = SCT.sc[a][0];
    const float ca = SCT.sc[a][1];
    #pragma unroll
    for (int i = 0; i < 2; ++i) {
        const int tile = t + 512 * i;          // by*32+bx
        const int bx = tile & 31, by = tile >> 5;
        const float xlo = (float)(240 - 16 * bx);   // min x over tile
        const float ylo = (float)(16 * by - 256);
        const float yhi = (float)(16 * by - 241);
        const float pmin = fmaf(sa, xlo, fminf(ca * ylo, ca * yhi) + 256.0f);
        const int base = ((int)floorf(pmin) - 2) & ~1;  // even, fp-slop safety
        qbt[tile * NA + a] = (float)(256 - base);
    }
}

// ---------------------------------------------------------------------------
// K3: backprojection, 4 batches per thread, 16x16 tile, 1024 blocks (r3's
// proven 16 waves/CU structure) -- with FP16 WINDOWS. A window position's
// 4 batches are 8B, so both bilinear taps are 16B total: the tap path is
// ONE 16B LDS access per pixel-angle instead of two ds_read_b128 -> the
// DS-pipe floor (which r3 sat at 98% of) halves. Accumulation stays f32
// (cvt folds into fma_mix). LDS 13.4KB; staging traffic halved.
// ---------------------------------------------------------------------------
__global__ __launch_bounds__(256) void ir_backproject(const _Float16* __restrict__ fil2h,
                                                      const float* __restrict__ qbt,
                                                      float* __restrict__ out) {
    __shared__ __align__(16) _Float16 win[ASEG * WSH + 16];   // 13.4 KB + slack

    const int t = threadIdx.x;
    const int w0 = blockIdx.x * TS, h0 = blockIdx.y * TS;
    const float* qrow = qbt + (blockIdx.y * 32 + blockIdx.x) * NA;  // tile bases

    const int w = w0 + (t & 15);
    const int h = h0 + (t >> 4);

    const int ix = 255 - w;              // reversed x axis
    const int iy = h - 256;
    const int m = (ix * ix + iy * iy) <= 256 * 256;

    float* o0 = out + (size_t)h * P + w;

    if (__syncthreads_count(m) == 0) {   // tile fully outside circle
        o0[0] = 0.f;
        o0[(size_t)P * P] = 0.f;
        o0[(size_t)2 * P * P] = 0.f;
        o0[(size_t)3 * P * P] = 0.f;
        return;
    }

    const float xf = (float)ix;
    const float yf = (float)iy;
    float acc0 = 0.f, acc1 = 0.f, acc2 = 0.f, acc3 = 0.f;

    #pragma unroll
    for (int seg = 0; seg < 3; ++seg) {
        const int A0 = seg * ASEG;

        // Phase B: stage this segment's fp16 windows (16B chunks, 2 pos ea).
        // base even -> src 16B-aligned: half off = a*FSH + FOFFH + 4*base + 8i.
        for (int idx = t; idx < ASEG * WCHK; idx += 256) {
            const int al = idx / WCHK;
            const int i = idx - al * WCHK;
            const int a = A0 + al;
            const int base = 256 - (int)qrow[a];          // lane-varying -> v-load
            const f4 vv = *(const f4*)(fil2h + a * FSH + FOFFH + 4 * base + 8 * i);
            *(f4*)(win + al * WSH + 8 * i) = vv;
        }
        __syncthreads();

        // Phase C: q = p - base in [~2, 26); j = trunc(q); 8 halves at 4j =
        // both taps x 4 batches -> one 16B LDS access, f32 accumulate.
        #pragma unroll 4
        for (int al = 0; al < ASEG; ++al) {
            const float ss = SCT.sc[A0 + al][0];          // wave-uniform -> s_load
            const float cc = SCT.sc[A0 + al][1];
            const float qb = qrow[A0 + al];               // wave-uniform -> s_load
            const float q = fmaf(xf, ss, fmaf(yf, cc, qb));
            const int j = (int)q;
            const float fr = FRACT(q);
            const float omf = 1.f - fr;
            const _Float16* wr = win + al * WSH + 4 * j;  // 8B-aligned
            const h4 W0 = *(const h4*)(wr);
            const h4 W1 = *(const h4*)(wr + 4);
            acc0 = fmaf(omf, (float)W0.x, fmaf(fr, (float)W1.x, acc0));
            acc1 = fmaf(omf, (float)W0.y, fmaf(fr, (float)W1.y, acc1));
            acc2 = fmaf(omf, (float)W0.z, fmaf(fr, (float)W1.z, acc2));
            acc3 = fmaf(omf, (float)W0.w, fmaf(fr, (float)W1.w, acc3));
        }
        if (seg < 2) __syncthreads();    // protect win before restage (uniform)
    }

    const float scale = (float)(M_PI / (2.0 * NA));
    o0[0]                 = m ? acc0 * scale : 0.f;
    o0[(size_t)P * P]     = m ? acc1 * scale : 0.f;
    o0[(size_t)2 * P * P] = m ? acc2 * scale : 0.f;
    o0[(size_t)3 * P * P] = m ? acc3 * scale : 0.f;
}

// ---------------------------------------------------------------------------
extern "C" void kernel_launch(void* const* d_in, const int* in_sizes, int n_in,
                              void* d_out, int out_size, void* d_ws, size_t ws_size,
                              hipStream_t stream) {
    const float* sino = (const float*)d_in[0];
    float* out = (float*)d_out;
    float* ws = (float*)d_ws;

    float* qbt = ws;                          // 1024 tiles * 180 floats
    _Float16* fil2h = (_Float16*)(ws + NTILES * NA + GUARD);  // 180*2176 halves, 16B aligned

    ir_filter<<<NA, 512, 0, stream>>>(sino, fil2h, qbt);

    dim3 gridB(P / TS, P / TS, 1);            // 1024 blocks, 4 batches in-block
    ir_backproject<<<gridB, 256, 0, stream>>>(fil2h, qbt, out);
}